// Round 3
// baseline (19.157 us; speedup 1.0000x reference)
//
#include <hip/hip_runtime.h>
#include <math.h>

#ifndef __has_builtin
#define __has_builtin(x) 0
#endif

__device__ __forceinline__ float fexp2(float v) {
#if __has_builtin(__builtin_amdgcn_exp2f)
  return __builtin_amdgcn_exp2f(v);
#else
  return exp2f(v);
#endif
}

constexpr int Bc  = 8;
constexpr int Nc  = 512;
constexpr int Mc  = 2048;
constexpr int CIN = 8;
constexpr int Cc  = 9;        // 1 + CIN
constexpr int Oc  = 64;
constexpr int SN  = 16;       // n-slices across blocks
constexpr int NS  = Nc / SN;  // 32 n per slice

// ---------------- K1: partial channel sums over an n-slice ----------------
// Lane owns one output row m; x/y accesses are block-uniform (scalar or
// broadcast loads). grid = Bc*(Mc/256)*SN = 1024 blocks -> 4 blocks/CU,
// 4 waves/SIMD for latency hiding.
__global__ __launch_bounds__(256, 4) void k1_partial(
    const float* __restrict__ xg, const float* __restrict__ yg,
    const float* __restrict__ tg, const float* __restrict__ sg,
    float* __restrict__ ws)
{
  const int bx = blockIdx.x;
  const int sl = bx & (SN - 1);
  const int mt = (bx >> 4) & 7;
  const int b  = bx >> 7;
  const int m  = mt * 256 + threadIdx.x;

  // exp(-0.5 d / s_c^2) = exp2(kk_c * d)
  float kk[Cc];
  bool uni = true;
  const float s0 = sg[0];
  #pragma unroll
  for (int c = 0; c < Cc; ++c) {
    const float s = sg[c];
    kk[c] = -0.72134752044448170f * __expf(-2.0f * s);  // -0.5*log2(e)*e^{-2 sigma}
    uni = uni && (s == s0);
  }

  const float tm = tg[b * Mc + m];
  const float* __restrict__ xb = xg + b * Nc + sl * NS;
  const float* __restrict__ yb = yg + (size_t)(b * Nc + sl * NS) * CIN;

  float acc[Cc];
  #pragma unroll
  for (int c = 0; c < Cc; ++c) acc[c] = 0.0f;

  if (uni) {
    const float q  = sqrtf(-kk[0]);
    const float tq = tm * q;
    #pragma unroll 8
    for (int n = 0; n < NS; ++n) {
      const float dq = xb[n] * q - tq;
      const float w  = fexp2(-dq * dq);
      acc[0] += w;
      #pragma unroll
      for (int c = 1; c < Cc; ++c) acc[c] += yb[n * CIN + (c - 1)] * w;
    }
  } else {
    #pragma unroll 4
    for (int n = 0; n < NS; ++n) {
      const float d  = xb[n] - tm;
      const float d2 = d * d;
      acc[0] += fexp2(d2 * kk[0]);
      #pragma unroll
      for (int c = 1; c < Cc; ++c) acc[c] += yb[n * CIN + (c - 1)] * fexp2(d2 * kk[c]);
    }
  }

  // ws[sl][b][c][m]: contiguous in m -> coalesced
  #pragma unroll
  for (int c = 0; c < Cc; ++c)
    ws[((size_t)(sl * Bc + b) * Cc + c) * Mc + m] = acc[c];
}

// ---------------- K2: reduce slices + density div + h @ W + bias ----------
// grid = Bc*(Mc/64) = 256 blocks; block handles 64 m's. Slice reduction is
// done in registers over fully-independent unrolled global loads (no LDS
// staging of partials).
__global__ __launch_bounds__(256, 2) void k2_final(
    const float* __restrict__ ws, const float* __restrict__ Wg,
    const float* __restrict__ bg, float* __restrict__ outg)
{
  __shared__ float hh[Cc][64];
  __shared__ float sW[Cc][Oc];
  __shared__ float sb2[Oc];

  const int tid = threadIdx.x;
  const int bx  = blockIdx.x;
  const int b   = bx >> 5;
  const int m0  = (bx & 31) * 64;

  for (int i = tid; i < Cc * Oc; i += 256) (&sW[0][0])[i] = Wg[i];
  if (tid < Oc) sb2[tid] = bg[tid];

  // 576 (c,mm) pairs over 256 threads; per pair sum 16 independent loads
  for (int i = tid; i < Cc * 64; i += 256) {
    const int c  = i >> 6;
    const int mm = i & 63;
    const size_t base = (size_t)b * Cc * Mc + (size_t)c * Mc + m0 + mm;
    float s = 0.0f;
    #pragma unroll
    for (int sl = 0; sl < SN; ++sl)
      s += ws[(size_t)sl * Bc * Cc * Mc + base];
    hh[c][mm] = s;
  }
  __syncthreads();

  const int oq  = tid & 15;   // o-quad 0..15
  const int mm0 = tid >> 4;   // 0..15
  float4 wr[Cc];
  #pragma unroll
  for (int c = 0; c < Cc; ++c)
    wr[c] = *reinterpret_cast<const float4*>(&sW[c][oq * 4]);
  const float4 bv = *reinterpret_cast<const float4*>(&sb2[oq * 4]);

  #pragma unroll
  for (int k = 0; k < 4; ++k) {
    const int mm = mm0 + k * 16;
    const float dens = hh[0][mm];              // broadcast within 16-lane group
    const float inv  = 1.0f / (dens + 1e-8f);
    float4 r = bv;
    r.x += dens * wr[0].x; r.y += dens * wr[0].y;
    r.z += dens * wr[0].z; r.w += dens * wr[0].w;
    #pragma unroll
    for (int c = 1; c < Cc; ++c) {
      const float h = hh[c][mm] * inv;
      r.x += h * wr[c].x; r.y += h * wr[c].y;
      r.z += h * wr[c].z; r.w += h * wr[c].w;
    }
    reinterpret_cast<float4*>(outg)[((size_t)(b * Mc + m0 + mm) * Oc + oq * 4) >> 2] = r;
  }
}

extern "C" void kernel_launch(void* const* d_in, const int* in_sizes, int n_in,
                              void* d_out, int out_size, void* d_ws, size_t ws_size,
                              hipStream_t stream) {
  const float* x  = (const float*)d_in[0];
  const float* y  = (const float*)d_in[1];
  const float* t  = (const float*)d_in[2];
  const float* s  = (const float*)d_in[3];
  const float* W  = (const float*)d_in[4];
  const float* bb = (const float*)d_in[5];
  float* out = (float*)d_out;
  float* ws  = (float*)d_ws;   // SN*Bc*Cc*Mc*4 = 9.4 MB << ws_size

  k1_partial<<<dim3(Bc * (Mc / 256) * SN), 256, 0, stream>>>(x, y, t, s, ws);
  k2_final<<<dim3(Bc * (Mc / 64)), 256, 0, stream>>>(ws, W, bb, out);
}

// Round 4
// 13.503 us; speedup vs baseline: 1.4187x; 1.4187x over previous
//
#include <hip/hip_runtime.h>
#include <math.h>

#ifndef __has_builtin
#define __has_builtin(x) 0
#endif

__device__ __forceinline__ float fexp2(float v) {
#if __has_builtin(__builtin_amdgcn_exp2f)
  return __builtin_amdgcn_exp2f(v);
#else
  return exp2f(v);
#endif
}

constexpr int Bc  = 8;
constexpr int Nc  = 512;
constexpr int Mc  = 2048;
constexpr int CIN = 8;
constexpr int Cc  = 9;      // 1 + CIN
constexpr int Oc  = 64;

constexpr int T   = 512;    // threads/block (8 waves)
constexpr int G   = 16;     // m-pair groups (MT=2 -> 32 m per block)
constexpr int S   = 32;     // n-slices = T/G
constexpr int NSL = Nc / S; // 16 n per slice
constexpr int MB  = 2 * G;  // 32 m per block
// grid = Bc*(Mc/MB) = 8*64 = 512 blocks -> 2 blocks/CU, 4 waves/SIMD

__global__ __launch_bounds__(T, 4) void fused(
    const float* __restrict__ xg, const float* __restrict__ yg,
    const float* __restrict__ tg, const float* __restrict__ sg,
    const float* __restrict__ Wg, const float* __restrict__ bg,
    float* __restrict__ outg)
{
  __shared__ float2 part[S][Cc][G + 1];  // +1 pad breaks bank alignment; 38.3 KB
  __shared__ float  sW[Cc][Oc];
  __shared__ float  sb[Oc];

  const int tid = threadIdx.x;
  const int bx  = blockIdx.x;
  const int b   = bx >> 6;
  const int m0  = (bx & 63) * MB;

  for (int i = tid; i < Cc * Oc; i += T) (&sW[0][0])[i] = Wg[i];
  if (tid < Oc) sb[tid] = bg[tid];

  // exp(-0.5 d / s_c^2) = exp2(kk_c * d)
  float kk[Cc];
  bool uni = true;
  const float s0 = sg[0];
  #pragma unroll
  for (int c = 0; c < Cc; ++c) {
    const float sv = sg[c];
    kk[c] = -0.72134752044448170f * __expf(-2.0f * sv);  // -0.5*log2(e)*e^{-2 sigma}
    uni = uni && (sv == s0);
  }

  const int g = tid & (G - 1);   // m-pair group
  const int s = tid >> 4;        // n-slice 0..31

  const float t0 = tg[b * Mc + m0 + g * 2 + 0];
  const float t1 = tg[b * Mc + m0 + g * 2 + 1];

  float acc[2][Cc];
  #pragma unroll
  for (int j = 0; j < 2; ++j)
    #pragma unroll
    for (int c = 0; c < Cc; ++c) acc[j][c] = 0.0f;

  const float*  xb = xg + b * Nc;
  const float4* yb = reinterpret_cast<const float4*>(yg + (size_t)b * Nc * CIN);

  if (uni) {
    const float q   = sqrtf(-kk[0]);
    const float tq0 = t0 * q, tq1 = t1 * q;
    #pragma unroll 4
    for (int i = 0; i < NSL; ++i) {
      const int n = s * NSL + i;
      const float xq = xb[n] * q;
      const float4 ya = yb[2 * n];
      const float4 yc = yb[2 * n + 1];
      const float yv[CIN] = {ya.x, ya.y, ya.z, ya.w, yc.x, yc.y, yc.z, yc.w};
      const float dq0 = xq - tq0;
      const float dq1 = xq - tq1;
      const float w0 = fexp2(-dq0 * dq0);
      const float w1 = fexp2(-dq1 * dq1);
      acc[0][0] += w0; acc[1][0] += w1;
      #pragma unroll
      for (int c = 1; c < Cc; ++c) {
        acc[0][c] += yv[c - 1] * w0;
        acc[1][c] += yv[c - 1] * w1;
      }
    }
  } else {
    #pragma unroll 2
    for (int i = 0; i < NSL; ++i) {
      const int n = s * NSL + i;
      const float xv = xb[n];
      const float4 ya = yb[2 * n];
      const float4 yc = yb[2 * n + 1];
      const float yv[CIN] = {ya.x, ya.y, ya.z, ya.w, yc.x, yc.y, yc.z, yc.w};
      const float d0 = xv - t0, d1 = xv - t1;
      const float d0sq = d0 * d0, d1sq = d1 * d1;
      acc[0][0] += fexp2(d0sq * kk[0]);
      acc[1][0] += fexp2(d1sq * kk[0]);
      #pragma unroll
      for (int c = 1; c < Cc; ++c) {
        acc[0][c] += yv[c - 1] * fexp2(d0sq * kk[c]);
        acc[1][c] += yv[c - 1] * fexp2(d1sq * kk[c]);
      }
    }
  }

  // partials -> LDS, tree-reduce over slices (steps 16,8,4,2; final pair in epilogue)
  #pragma unroll
  for (int c = 0; c < Cc; ++c)
    part[s][c][g] = make_float2(acc[0][c], acc[1][c]);
  __syncthreads();

  #pragma unroll
  for (int step = 16; step >= 2; step >>= 1) {
    if (s < step) {
      #pragma unroll
      for (int c = 0; c < Cc; ++c) {
        const float2 a2 = part[s + step][c][g];
        const float2 b2 = part[s][c][g];
        part[s][c][g] = make_float2(a2.x + b2.x, a2.y + b2.y);
      }
    }
    __syncthreads();
  }

  // epilogue: one float4 of output per thread
  const int oq = tid & 15;   // o-quad
  const int mm = tid >> 4;   // 0..31 m within tile
  const int gg = mm >> 1;
  const int hf = mm & 1;

  float hv[Cc];
  #pragma unroll
  for (int c = 0; c < Cc; ++c) {
    const float2 p0 = part[0][c][gg];
    const float2 p1 = part[1][c][gg];
    hv[c] = hf ? (p0.y + p1.y) : (p0.x + p1.x);
  }

  const float dens = hv[0];
  const float inv  = 1.0f / (dens + 1e-8f);
  float4 r = *reinterpret_cast<const float4*>(&sb[oq * 4]);
  {
    const float4 w0 = *reinterpret_cast<const float4*>(&sW[0][oq * 4]);
    r.x += dens * w0.x; r.y += dens * w0.y;
    r.z += dens * w0.z; r.w += dens * w0.w;
  }
  #pragma unroll
  for (int c = 1; c < Cc; ++c) {
    const float h = hv[c] * inv;
    const float4 wc = *reinterpret_cast<const float4*>(&sW[c][oq * 4]);
    r.x += h * wc.x; r.y += h * wc.y;
    r.z += h * wc.z; r.w += h * wc.w;
  }
  reinterpret_cast<float4*>(outg)[((size_t)(b * Mc + m0 + mm) * Oc + oq * 4) >> 2] = r;
}

extern "C" void kernel_launch(void* const* d_in, const int* in_sizes, int n_in,
                              void* d_out, int out_size, void* d_ws, size_t ws_size,
                              hipStream_t stream) {
  const float* x  = (const float*)d_in[0];
  const float* y  = (const float*)d_in[1];
  const float* t  = (const float*)d_in[2];
  const float* s  = (const float*)d_in[3];
  const float* W  = (const float*)d_in[4];
  const float* bb = (const float*)d_in[5];
  float* out = (float*)d_out;

  fused<<<dim3(Bc * (Mc / MB)), T, 0, stream>>>(x, y, t, s, W, bb, out);
}